// Round 8
// baseline (75096.185 us; speedup 1.0000x reference)
//
#include <hip/hip_runtime.h>
#include <hip/hip_bf16.h>
#include <cstdint>
#include <cstddef>
#include <cstring>

using u32 = unsigned int;
using u64 = unsigned long long;
typedef _Float16 h2 __attribute__((ext_vector_type(2)));
typedef _Float16 h4 __attribute__((ext_vector_type(4)));

constexpr int B_=64, T_=600, U_=50, V_=77, H_=400, OUT_=121;
constexpr int G1=50, G2=50, G3=50, GOUT=8;
constexpr int NBLK = G1+G2+G3+GOUT; // 158
constexpr int TF0=G1, TF1=8, TF2=G2, TF3=G3;

// ---- ws byte offsets ----
constexpr size_t FLAGS_B = 0;                        // [stage5][t600][prod64] 16B slots
constexpr size_t FLAGS_SZ = 5ull*600*64*16;          // 3,072,000
constexpr size_t HS1P_B = 3072256;                   // u32 [2][64][200] f16-pair ping-pong
constexpr size_t HSPSZ  = 2ull*64*200*4;             // 102,400
constexpr size_t HS2P_B = HS1P_B + HSPSZ;
constexpr size_t HS3P_B = HS2P_B + HSPSZ;
constexpr size_t W1F_B  = HS3P_B + HSPSZ;            // interleaved f16 [kk][cu8][g4][h4]
constexpr size_t W1WG   = 120ull*128;
constexpr size_t W2F_B  = W1F_B + 50ull*W1WG*2;
constexpr size_t W2WG   = 220ull*128;
constexpr size_t W3F_B  = W2F_B + 50ull*W2WG*2;
constexpr size_t WOF_B  = W3F_B + 50ull*W2WG*2;      // 8 * [kk300][cg32][c4][h4]
constexpr size_t WOWG   = 300ull*32*16;
constexpr size_t WWF_B  = WOF_B + 8ull*WOWG*2;       // 50 * u32 [kk200][m32] f16-pairs
constexpr size_t WWFWG  = 200ull*32;
constexpr size_t FF2_B  = WWF_B + 50ull*WWFWG*4;     // u32 [600][64][240]
constexpr size_t FFSZ   = 600ull*64*240*4;
constexpr size_t FF3_B  = FF2_B + FFSZ;
constexpr size_t H3R_B  = FF3_B + FFSZ;              // u32 [64][64][200] ring
// total ~94 MB

// ---- LDS layout ----
// L1: panA[64][180]f16 | panB[64][180]f16 | panC[64][52]f16 | mix[64][30]f32 | kap[64][10]f32
//     aliases: wvacc f32[64][77] over panA; phi f32[64][50] at PANB; wvpan u32[64][40] at PANB+12800
constexpr int SW1F = 180, SW1C = 52;
constexpr int PANB_O = 23040, PANC_O = 46080, MIX_O = 52736, KAP_O = 60416;
constexpr int SW2 = 228;   // L2/L3 panels (220 dims)
constexpr int SWO = 244;   // OUT
constexpr int SMEM_BYTES = 62976;

struct P {
  const float *x, *tmask, *h0, *c0, *pwv, *pkap;
  const int *text;
  const float *wih1,*whh1,*bih1,*bhh1;
  const float *wih2,*whh2,*bih2,*bhh2;
  const float *wih3,*whh3,*bih3,*bhh3;
  const float *wwin,*bwin,*wout,*bout;
  float *out_y,*out_wv,*out_kap;
  u32 *hs1,*hs2,*hs3;          // f16-pair ping-pong states
  _Float16 *w1f,*w2f,*w3f,*wof;
  u32 *wwf;                    // window weight f16-pairs [wg][kk][m32]
  u32 *ff2,*ff3,*h3r;
  u32 *flags;
};

// ---- coherent (agent-scope) helpers ----
__device__ __forceinline__ float ldc_f(const float* p) {
  return __hip_atomic_load((float*)p, __ATOMIC_RELAXED, __HIP_MEMORY_SCOPE_AGENT);
}
__device__ __forceinline__ void stc_f(float* p, float v) {
  __hip_atomic_store(p, v, __ATOMIC_RELAXED, __HIP_MEMORY_SCOPE_AGENT);
}
__device__ __forceinline__ u32 ldc_u(const u32* p) {
  return __hip_atomic_load((u32*)p, __ATOMIC_RELAXED, __HIP_MEMORY_SCOPE_AGENT);
}
__device__ __forceinline__ void stc_u(u32* p, u32 v) {
  __hip_atomic_store(p, v, __ATOMIC_RELAXED, __HIP_MEMORY_SCOPE_AGENT);
}
__device__ __forceinline__ float sigm(float x) { return 1.f/(1.f+__expf(-x)); }
__device__ __forceinline__ h2 pk16(float a, float b) {
  auto t = __builtin_amdgcn_cvt_pkrtz(a, b);
  h2 r; memcpy(&r, &t, 4); return r;
}
__device__ __forceinline__ u32 h2u(h2 v) { u32 r; memcpy(&r, &v, 4); return r; }
__device__ __forceinline__ h2 u2h(u32 v) { h2 r; memcpy(&r, &v, 4); return r; }
__device__ __forceinline__ float dot2(h2 a, h2 b, float c) { return __builtin_amdgcn_fdot2(a, b, c, false); }
__device__ __forceinline__ h2 lo4(h4 v) { return __builtin_shufflevector(v, v, 0, 1); }
__device__ __forceinline__ h2 hi4(h4 v) { return __builtin_shufflevector(v, v, 2, 3); }

__device__ __forceinline__ void poll_all(u32* flags, int stage, int t, int n) {
  const size_t base = ((size_t)stage*600 + t) * 64;
  for (int i = threadIdx.x; i < n; i += 256) {
    const u32* s = flags + ((base + i) << 2);
    int spins = 0;
    while (ldc_u(s) == 0) { if (++spins > 8) __builtin_amdgcn_s_sleep(1); }
  }
}
__device__ __forceinline__ void set_flag(u32* flags, int stage, int t, int prod) {
  if (threadIdx.x == 0)
    stc_u(flags + ((((size_t)stage*600 + t)*64 + prod) << 2), 1u);
}

// gemm phase over interleaved weights [kk][cu8][g4][h4]
template<int PH>
__device__ __forceinline__ void gemm_phase(const _Float16* pan, int SWf, const _Float16* wgW,
                                           int cu, int kbase, int b0, float acc[2][4]) {
  const _Float16* a0 = pan + b0*SWf;
  const _Float16* a1 = a0 + SWf;
  const _Float16* wp = wgW + ((size_t)(kbase >> 2) * 8 + cu) * 16;
#pragma unroll 4
  for (int k = 0; k < PH; k += 4) {
    h4 x0 = *(const h4*)(a0+k), x1 = *(const h4*)(a1+k);
    h4 wa = *(const h4*)(wp);
    h4 wb = *(const h4*)(wp+4);
    h4 wc = *(const h4*)(wp+8);
    h4 wd = *(const h4*)(wp+12);
    wp += 128;
    h2 x0l=lo4(x0), x0h=hi4(x0), x1l=lo4(x1), x1h=hi4(x1);
    acc[0][0]=dot2(x0l,lo4(wa),acc[0][0]); acc[0][0]=dot2(x0h,hi4(wa),acc[0][0]);
    acc[0][1]=dot2(x0l,lo4(wb),acc[0][1]); acc[0][1]=dot2(x0h,hi4(wb),acc[0][1]);
    acc[0][2]=dot2(x0l,lo4(wc),acc[0][2]); acc[0][2]=dot2(x0h,hi4(wc),acc[0][2]);
    acc[0][3]=dot2(x0l,lo4(wd),acc[0][3]); acc[0][3]=dot2(x0h,hi4(wd),acc[0][3]);
    acc[1][0]=dot2(x1l,lo4(wa),acc[1][0]); acc[1][0]=dot2(x1h,hi4(wa),acc[1][0]);
    acc[1][1]=dot2(x1l,lo4(wb),acc[1][1]); acc[1][1]=dot2(x1h,hi4(wb),acc[1][1]);
    acc[1][2]=dot2(x1l,lo4(wc),acc[1][2]); acc[1][2]=dot2(x1h,hi4(wc),acc[1][2]);
    acc[1][3]=dot2(x1l,lo4(wd),acc[1][3]); acc[1][3]=dot2(x1h,hi4(wd),acc[1][3]);
  }
}

// window mix partial: mix[b][m] += pan[b][k-pairs] . wwf[pairBase+j][m]
__device__ __forceinline__ void mix_partial(const _Float16* pan, int SWf, const u32* wwf,
                                            int pairBase, int npairs, float* mixL, int tid) {
#pragma unroll 2
  for (int it = 0; it < 8; ++it) {
    int item = tid + it*256; if (item >= 1920) break;
    int b = item / 30, m = item - (item/30)*30;
    const u32* row = (const u32*)(pan + b*SWf);
    float d = mixL[b*30 + m];
#pragma unroll 8
    for (int j = 0; j < npairs; ++j)
      d = dot2(u2h(row[j]), u2h(wwf[(size_t)(pairBase + j)*32 + m]), d);
    mixL[b*30 + m] = d;
  }
}

// ================= L1 + fused attention =================
__device__ void lstm1_role(const P& p, int wg, char* smem) {
  const int tid = threadIdx.x, cg = tid & 7, tb = tid >> 3;
  const int u = wg*8 + cg, b0 = tb*2;
  _Float16* panA = (_Float16*)smem;
  _Float16* panB = (_Float16*)(smem + PANB_O);
  _Float16* panC = (_Float16*)(smem + PANC_O);
  float* wva  = (float*)smem;                 // alias panA [64][77] f32
  float* phiL = (float*)(smem + PANB_O);      // alias panB [64][50] f32
  u32* wvpan  = (u32*)(smem + PANB_O + 12800);// alias panB [64][40] u32
  float* mixL = (float*)(smem + MIX_O);       // [64][30]
  float* kapL = (float*)(smem + KAP_O);       // [64][10]
  _Float16* wgW = p.w1f + (size_t)wg * W1WG;
  u32* wwf = p.wwf + (size_t)wg * WWFWG;

  // one-time repacks (own-wg regions, same-wg rd)
  for (int e = tid; e < 32*480; e += 256) {
    int lr = e / 480, j = e - lr*480;
    int g = lr >> 3, cu = lr & 7;
    int r = g*400 + wg*8 + cu;
    float v;
    if (j < 400)      v = p.whh1[(size_t)r*400 + j];
    else if (j < 477) v = p.wih1[(size_t)r*80 + 3 + (j-400)];
    else              v = p.wih1[(size_t)r*80 + (j-477)];
    wgW[((size_t)(j>>2)*8 + cu)*16 + g*4 + (j&3)] = (_Float16)v;
  }
  for (int e = tid; e < 200*30; e += 256) {
    int kk = e / 30, m = e - (e/30)*30;
    wwf[(size_t)kk*32 + m] = h2u(pk16(p.wwin[(size_t)m*400 + 2*kk],
                                      p.wwin[(size_t)m*400 + 2*kk + 1]));
  }
  for (int i = tid; i < 640; i += 256) kapL[i] = p.pkap[i];   // [64][10]
  float bsum[4];
#pragma unroll
  for (int g = 0; g < 4; ++g) bsum[g] = p.bih1[g*400+u] + p.bhh1[g*400+u];
  float creg[2];
  creg[0] = p.c0[(size_t)b0*H_ + u];
  creg[1] = p.c0[(size_t)(b0+1)*H_ + u];
  float bwin_r[30];
#pragma unroll
  for (int m = 0; m < 30; ++m) bwin_r[m] = p.bwin[m];
  __syncthreads();

  for (int t = 0; t < T_; ++t) {
    const int par = t & 1;
    const u32* hsrcP = p.hs1 + (size_t)(par^1)*12800;
    float acc[2][4] = {{0,0,0,0},{0,0,0,0}};

    if (t > 0) poll_all(p.flags, 0, t-1, TF0);
    __syncthreads();
    // I2: stage ph0 (pairs 0..88) + zero mix
    {
      u32 tmp[22];
#pragma unroll
      for (int it = 0; it < 22; ++it) {
        int idx = tid + it*256; int b = idx/88, pp = idx - b*88;
        if (t == 0) { float2 f = *(const float2*)(p.h0 + (size_t)b*H_ + 2*pp); tmp[it] = h2u(pk16(f.x, f.y)); }
        else tmp[it] = ldc_u(hsrcP + b*200 + pp);
      }
      for (int i = tid; i < 1920; i += 256) mixL[i] = 0.f;
#pragma unroll
      for (int it = 0; it < 22; ++it) {
        int idx = tid + it*256; int b = idx/88, pp = idx - b*88;
        ((u32*)panA)[b*90 + pp] = tmp[it];
      }
    }
    __syncthreads();
    // I3: stage ph1 (88..176) || gemm0 + mixp0 (panA)
    {
      u32 tmp[22];
#pragma unroll
      for (int it = 0; it < 22; ++it) {
        int idx = tid + it*256; int b = idx/88, pp = 88 + (idx - b*88);
        if (t == 0) { float2 f = *(const float2*)(p.h0 + (size_t)b*H_ + 2*pp); tmp[it] = h2u(pk16(f.x, f.y)); }
        else tmp[it] = ldc_u(hsrcP + b*200 + pp);
      }
      gemm_phase<176>(panA, SW1F, wgW, cg, 0, b0, acc);
      mix_partial(panA, SW1F, wwf, 0, 88, mixL, tid);
#pragma unroll
      for (int it = 0; it < 22; ++it) {
        int idx = tid + it*256; int b = idx/88, pp = idx - b*88;
        ((u32*)panB)[b*90 + pp] = tmp[it];
      }
    }
    __syncthreads();
    // I4: stage ph2 (176..200 -> panC) || gemm1 + mixp1 (panB)
    {
      u32 tmp[6];
#pragma unroll
      for (int it = 0; it < 6; ++it) {
        int idx = tid + it*256; if (idx >= 64*24) break;
        int b = idx/24, pp = 176 + (idx - b*24);
        if (t == 0) { float2 f = *(const float2*)(p.h0 + (size_t)b*H_ + 2*pp); tmp[it] = h2u(pk16(f.x, f.y)); }
        else tmp[it] = ldc_u(hsrcP + b*200 + pp);
      }
      gemm_phase<176>(panB, SW1F, wgW, cg, 176, b0, acc);
      mix_partial(panB, SW1F, wwf, 88, 88, mixL, tid);
#pragma unroll
      for (int it = 0; it < 6; ++it) {
        int idx = tid + it*256; if (idx >= 64*24) break;
        int b = idx/24, pp = idx - b*24;
        ((u32*)panC)[b*26 + pp] = tmp[it];
      }
    }
    __syncthreads();
    // I5: gemm2 + mixp2 (panC)
    gemm_phase<48>(panC, SW1C, wgW, cg, 352, b0, acc);
    mix_partial(panC, SW1C, wwf, 176, 24, mixL, tid);
    __syncthreads();
    if (t > 0) {
      // I6: exp(mix+bwin); kappa update; zero wvacc
      for (int i = tid; i < 1920; i += 256) {
        int m = i - (i/30)*30;
        mixL[i] = __expf(mixL[i] + bwin_r[m]);
      }
      __syncthreads();
      for (int i = tid; i < 640; i += 256) {
        int b = i / 10, k = i - (i/10)*10;
        kapL[i] += mixL[b*30 + 20 + k];
      }
      for (int i = tid; i < 64*77; i += 256) wva[i] = 0.f;
      __syncthreads();
      // I7: phi
      for (int i = tid; i < 3200; i += 256) {
        int b = i / 50, uu = i - (i/50)*50;
        const float fu = (float)uu;
        float s = 0.f;
#pragma unroll
        for (int k = 0; k < 10; ++k) {
          float df = kapL[b*10+k] - fu;
          s += mixL[b*30+k] * __expf(-mixL[b*30+10+k]*df*df);
        }
        phiL[i] = s * p.tmask[(size_t)b*U_ + uu];
      }
      __syncthreads();
      // I8: scatter (serial per batch)
      if (tid < 64) {
        const int b = tid;
        for (int uu = 0; uu < U_; ++uu)
          wva[b*77 + p.text[(size_t)b*U_ + uu]] += phiL[b*50 + uu];
      }
      __syncthreads();
    } else {
      // t==0: wv(-1) = pwv
      __syncthreads();  // match I6 barrier count? not needed for correctness of LDS since branch wg-uniform
      for (int i = tid; i < 64*77; i += 256) wva[i] = p.pwv[i];
      __syncthreads();
    }
    // I9: pack wv+x panel; writers store out_wv(t-1)/ff(t-1)
    for (int i = tid; i < 64*40; i += 256) {
      int b = i / 40, pr = i - (i/40)*40;
      float f0, f1;
      if (pr < 38)       { f0 = wva[b*77 + 2*pr]; f1 = wva[b*77 + 2*pr + 1]; }
      else if (pr == 38) { f0 = wva[b*77 + 76];   f1 = p.x[((size_t)b*T_ + t)*3 + 0]; }
      else               { f0 = p.x[((size_t)b*T_ + t)*3 + 1]; f1 = p.x[((size_t)b*T_ + t)*3 + 2]; }
      wvpan[i] = h2u(pk16(f0, f1));
    }
    if (wg < 8 && t > 0) {
      const int bw0 = wg*8;
      for (int i = tid; i < 8*77; i += 256) {
        int bl = i / 77, v = i - (i/77)*77;
        stc_f(p.out_wv + ((size_t)(bw0+bl)*T_ + (t-1))*V_ + v, wva[(bw0+bl)*77 + v]);
      }
      for (int i = tid; i < 8*40; i += 256) {
        int bl = i / 40, pr = i - (i/40)*40;
        int b = bw0 + bl;
        float f0, f1;
        if (pr < 38)       { f0 = wva[b*77 + 2*pr]; f1 = wva[b*77 + 2*pr + 1]; }
        else if (pr == 38) { f0 = wva[b*77 + 76];   f1 = p.x[((size_t)b*T_ + (t-1))*3 + 0]; }
        else               { f0 = p.x[((size_t)b*T_ + (t-1))*3 + 1]; f1 = p.x[((size_t)b*T_ + (t-1))*3 + 2]; }
        u32 pk = h2u(pk16(f0, f1));
        stc_u(p.ff2 + ((size_t)(t-1)*64 + b)*240 + pr, pk);
        stc_u(p.ff3 + ((size_t)(t-1)*64 + b)*240 + pr, pk);
      }
    }
    __syncthreads();
    // I10: gate tail (wv+x, k 400..480) + cell + stores
    gemm_phase<80>((const _Float16*)wvpan, 80, wgW, cg, 400, b0, acc);
    float hn[2];
#pragma unroll
    for (int r = 0; r < 2; ++r) {
      float gi = acc[r][0]+bsum[0], gf = acc[r][1]+bsum[1];
      float gg = acc[r][2]+bsum[2], go = acc[r][3]+bsum[3];
      float cn = sigm(gf)*creg[r] + sigm(gi)*tanhf(gg);
      creg[r] = cn;
      hn[r] = sigm(go)*tanhf(cn);
    }
    {
      float h0p = __shfl_xor(hn[0], 1, 64);
      float h1p = __shfl_xor(hn[1], 1, 64);
      if ((cg & 1) == 0) {
        const int pi = wg*4 + (cg >> 1);
        u32 pk0 = h2u(pk16(hn[0], h0p));
        u32 pk1 = h2u(pk16(hn[1], h1p));
        stc_u(p.hs1 + (size_t)par*12800 + b0*200 + pi, pk0);
        stc_u(p.hs1 + (size_t)par*12800 + (b0+1)*200 + pi, pk1);
        stc_u(p.ff2 + ((size_t)t*64 + b0)*240 + 40 + pi, pk0);
        stc_u(p.ff2 + ((size_t)t*64 + b0+1)*240 + 40 + pi, pk1);
      }
    }
    __syncthreads();
    set_flag(p.flags, 0, t, wg);
    if (wg < 8 && t > 0) set_flag(p.flags, 1, t-1, wg);
  }

  // ---- epilogue: window(599) -> out_wv(599), ff(599), out_kap ----
  if (wg < 8) {
    poll_all(p.flags, 0, 599, TF0);
    __syncthreads();
    const u32* hsrcP = p.hs1 + (size_t)(599&1)*12800;
    for (int i = tid; i < 1920; i += 256) mixL[i] = 0.f;
    for (int it = 0; it < 50; ++it) {
      int idx = tid + it*256; if (idx >= 64*200) break;
      int b = idx/200, pp = idx - b*200;
      if (pp < 176) ((u32*)((pp < 88) ? (u32*)panA : (u32*)panB))[b*90 + (pp % 88)] = ldc_u(hsrcP + b*200 + pp);
      else ((u32*)panC)[b*26 + (pp-176)] = ldc_u(hsrcP + b*200 + pp);
    }
    __syncthreads();
    mix_partial(panA, SW1F, wwf, 0, 88, mixL, tid);
    __syncthreads();
    mix_partial(panB, SW1F, wwf, 88, 88, mixL, tid);
    __syncthreads();
    mix_partial(panC, SW1C, wwf, 176, 24, mixL, tid);
    __syncthreads();
    for (int i = tid; i < 1920; i += 256) {
      int m = i - (i/30)*30;
      mixL[i] = __expf(mixL[i] + bwin_r[m]);
    }
    __syncthreads();
    for (int i = tid; i < 640; i += 256) {
      int b = i / 10, k = i - (i/10)*10;
      kapL[i] += mixL[b*30 + 20 + k];
    }
    for (int i = tid; i < 64*77; i += 256) wva[i] = 0.f;
    __syncthreads();
    for (int i = tid; i < 3200; i += 256) {
      int b = i / 50, uu = i - (i/50)*50;
      const float fu = (float)uu;
      float s = 0.f;
#pragma unroll
      for (int k = 0; k < 10; ++k) {
        float df = kapL[b*10+k] - fu;
        s += mixL[b*30+k] * __expf(-mixL[b*30+10+k]*df*df);
      }
      phiL[i] = s * p.tmask[(size_t)b*U_ + uu];
    }
    __syncthreads();
    if (tid < 64) {
      const int b = tid;
      for (int uu = 0; uu < U_; ++uu)
        wva[b*77 + p.text[(size_t)b*U_ + uu]] += phiL[b*50 + uu];
    }
    __syncthreads();
    const int bw0 = wg*8;
    for (int i = tid; i < 8*77; i += 256) {
      int bl = i / 77, v = i - (i/77)*77;
      stc_f(p.out_wv + ((size_t)(bw0+bl)*T_ + 599)*V_ + v, wva[(bw0+bl)*77 + v]);
    }
    for (int i = tid; i < 8*40; i += 256) {
      int bl = i / 40, pr = i - (i/40)*40;
      int b = bw0 + bl;
      float f0, f1;
      if (pr < 38)       { f0 = wva[b*77 + 2*pr]; f1 = wva[b*77 + 2*pr + 1]; }
      else if (pr == 38) { f0 = wva[b*77 + 76];   f1 = p.x[((size_t)b*T_ + 599)*3 + 0]; }
      else               { f0 = p.x[((size_t)b*T_ + 599)*3 + 1]; f1 = p.x[((size_t)b*T_ + 599)*3 + 2]; }
      u32 pk = h2u(pk16(f0, f1));
      stc_u(p.ff2 + ((size_t)599*64 + b)*240 + pr, pk);
      stc_u(p.ff3 + ((size_t)599*64 + b)*240 + pr, pk);
    }
    for (int i = tid; i < 80; i += 256) {
      int bl = i / 10, k = i - (i/10)*10;
      stc_f(p.out_kap + (size_t)(bw0+bl)*10 + k, kapL[(bw0+bl)*10 + k]);
    }
    __syncthreads();
    set_flag(p.flags, 1, 599, wg);
  }
}

// ================= L2/L3 =================
template <int L>
__device__ void lstm_role(const P& p, int wg, char* smem) {
  const int tid = threadIdx.x, cg = tid & 7, tb = tid >> 3;
  const int u = wg*8 + cg, b0 = tb*2;
  constexpr int STG = (L==2) ? 2 : 3;
  _Float16* wf = (L==2) ? p.w2f : p.w3f;
  _Float16* wgW = wf + (size_t)wg * W2WG;
  const float* wih = (L==2) ? p.wih2 : p.wih3;
  const float* whh = (L==2) ? p.whh2 : p.whh3;
  const float* bih = (L==2) ? p.bih2 : p.bih3;
  const float* bhh = (L==2) ? p.bhh2 : p.bhh3;
  u32* hsP = (L==2) ? p.hs2 : p.hs3;
  const u32* ffin = (L==3) ? p.ff3 : p.ff2;
  _Float16* panA = (_Float16*)smem;
  _Float16* panB = panA + 64*SW2;

  for (int e = tid; e < 32*880; e += 256) {
    int lr = e / 880, j = e - lr*880;
    int g = lr >> 3, cu = lr & 7;
    int r = g*400 + wg*8 + cu;
    float v;
    if (j < 77)       v = wih[(size_t)r*480 + 403 + j];
    else if (j < 80)  v = wih[(size_t)r*480 + (j-77)];
    else if (j < 480) v = wih[(size_t)r*480 + 3 + (j-80)];
    else              v = whh[(size_t)r*400 + (j-480)];
    wgW[((size_t)(j>>2)*8 + cu)*16 + g*4 + (j&3)] = (_Float16)v;
  }
  float bsum[4];
#pragma unroll
  for (int g = 0; g < 4; ++g) bsum[g] = bih[g*400+u] + bhh[g*400+u];
  float creg[2];
  creg[0] = p.c0[(size_t)(L-1)*B_*H_ + (size_t)b0*H_ + u];
  creg[1] = p.c0[(size_t)(L-1)*B_*H_ + (size_t)(b0+1)*H_ + u];
  __syncthreads();

  for (int t = 0; t < T_; ++t) {
    const int par = t & 1;
    const u32* hsrcP = hsP + (size_t)(par^1)*12800;
    const float* h0f = p.h0 + (size_t)(L-1)*B_*H_;
    float acc[2][4] = {{0,0,0,0},{0,0,0,0}};

    // K-order: [wv77 x3 | hin400 | hrec400]; ff pairs 0..240, rec pairs 0..200
    poll_all(p.flags, 1, t, TF1);
    poll_all(p.flags, (L==2) ? 0 : 2, t, 50);
    if (L == 3 && t >= 64) poll_all(p.flags, 4, t-64, 1);
    __syncthreads();
    {
      u32 tmp[28];
#pragma unroll
      for (int it = 0; it < 28; ++it) {
        int idx = tid + it*256; if (idx >= 64*110) break;
        int b = idx/110, pl = idx - b*110;
        tmp[it] = ldc_u(ffin + ((size_t)t*64 + b)*240 + pl);
      }
#pragma unroll
      for (int it = 0; it < 28; ++it) {
        int idx = tid + it*256; if (idx >= 64*110) break;
        int b = idx/110, pl = idx - b*110;
        *(u32*)(panA + b*SW2 + 2*pl) = tmp[it];
      }
    }
    __syncthreads();
    {
      u32 tmp[28];
#pragma unroll
      for (int it = 0; it < 28; ++it) {
        int idx = tid + it*256; if (idx >= 64*110) break;
        int b = idx/110, pl = idx - b*110;
        tmp[it] = ldc_u(ffin + ((size_t)t*64 + b)*240 + 110 + pl);
      }
      gemm_phase<220>(panA, SW2, wgW, cg, 0, b0, acc);
#pragma unroll
      for (int it = 0; it < 28; ++it) {
        int idx = tid + it*256; if (idx >= 64*110) break;
        int b = idx/110, pl = idx - b*110;
        *(u32*)(panB + b*SW2 + 2*pl) = tmp[it];
      }
    }
    if (t > 0) poll_all(p.flags, STG, t-1, 50);
    __syncthreads();
    {
      u32 tmp[28];
#pragma unroll
      for (int it = 0; it < 28; ++it) {
        int idx = tid + it*256; if (idx >= 64*110) break;
        int b = idx/110, pl = idx - b*110;
        u32 pv;
        if (pl < 20) pv = ldc_u(ffin + ((size_t)t*64 + b)*240 + 220 + pl);
        else if (t == 0) { float2 f = *(const float2*)(h0f + (size_t)b*H_ + 2*(pl-20)); pv = h2u(pk16(f.x, f.y)); }
        else pv = ldc_u(hsrcP + b*200 + (pl-20));
        tmp[it] = pv;
      }
      gemm_phase<220>(panB, SW2, wgW, cg, 220, b0, acc);
#pragma unroll
      for (int it = 0; it < 28; ++it) {
        int idx = tid + it*256; if (idx >= 64*110) break;
        int b = idx/110, pl = idx - b*110;
        *(u32*)(panA + b*SW2 + 2*pl) = tmp[it];
      }
    }
    __syncthreads();
    {
      u32 tmp[28];
#pragma unroll
      for (int it = 0; it < 28; ++it) {
        int idx = tid + it*256; if (idx >= 64*110) break;
        int b = idx/110, pl = idx - b*110;
        u32 pv;
        if (t == 0) { float2 f = *(const float2*)(h0f + (size_t)b*H_ + 2*(90+pl)); pv = h2u(pk16(f.x, f.y)); }
        else pv = ldc_u(hsrcP + b*200 + 90 + pl);
        tmp[it] = pv;
      }
      gemm_phase<220>(panA, SW2, wgW, cg, 440, b0, acc);
#pragma unroll
      for (int it = 0; it < 28; ++it) {
        int idx = tid + it*256; if (idx >= 64*110) break;
        int b = idx/110, pl = idx - b*110;
        *(u32*)(panB + b*SW2 + 2*pl) = tmp[it];
      }
    }
    __syncthreads();
    gemm_phase<220>(panB, SW2, wgW, cg, 660, b0, acc);

    float hn[2];
#pragma unroll
    for (int r = 0; r < 2; ++r) {
      float gi = acc[r][0]+bsum[0], gf = acc[r][1]+bsum[1];
      float gg = acc[r][2]+bsum[2], go = acc[r][3]+bsum[3];
      float cn = sigm(gf)*creg[r] + sigm(gi)*tanhf(gg);
      creg[r] = cn;
      hn[r] = sigm(go)*tanhf(cn);
    }
    {
      float h0p = __shfl_xor(hn[0], 1, 64);
      float h1p = __shfl_xor(hn[1], 1, 64);
      if ((cg & 1) == 0) {
        const int pi = wg*4 + (cg >> 1);
        u32 pk0 = h2u(pk16(hn[0], h0p));
        u32 pk1 = h2u(pk16(hn[1], h1p));
        stc_u(hsP + (size_t)par*12800 + b0*200 + pi, pk0);
        stc_u(hsP + (size_t)par*12800 + (b0+1)*200 + pi, pk1);
        if (L == 2) {
          stc_u(p.ff3 + ((size_t)t*64 + b0)*240 + 40 + pi, pk0);
          stc_u(p.ff3 + ((size_t)t*64 + b0+1)*240 + 40 + pi, pk1);
        } else {
          stc_u(p.h3r + ((size_t)(t&63)*64 + b0)*200 + pi, pk0);
          stc_u(p.h3r + ((size_t)(t&63)*64 + b0+1)*200 + pi, pk1);
        }
      }
    }
    __syncthreads();
    set_flag(p.flags, STG, t, wg);
  }
}

// ================= output projection =================
__device__ void out_role(const P& p, int g, char* smem) {
  const int tid = threadIdx.x;
  const int cg = tid & 31, bg = tid >> 5;
  const int c0 = cg*4;
  _Float16* pan = (_Float16*)smem;
  _Float16* wofg = p.wof + (size_t)g*WOWG;
  for (int e = tid; e < 300*32*16; e += 256) {
    int kk = e >> 9, rem = e & 511;
    int cgi = rem >> 4, j4 = rem & 15;
    int j = j4 >> 2, kc = j4 & 3;
    int c = cgi*4 + j; if (c > 120) c = 120;
    wofg[e] = (_Float16)p.wout[(size_t)c*1200 + kk*4 + kc];
  }
  float bo[4];
#pragma unroll
  for (int j = 0; j < 4; ++j) {
    int c = c0 + j; if (c > 120) c = 120;
    bo[j] = p.bout[c];
  }
  __syncthreads();

  for (int t = g; t < T_; t += GOUT) {
    poll_all(p.flags, 3, t, TF3);
    __syncthreads();
    float acc[8][4];
#pragma unroll
    for (int r = 0; r < 8; ++r)
#pragma unroll
      for (int j = 0; j < 4; ++j) acc[r][j] = 0.f;

    for (int ph = 0; ph < 5; ++ph) {
      for (int idx = tid; idx < 64*120; idx += 256) {
        int b = idx / 120, pl = idx - b*120;
        int Pp = ph*120 + pl;
        u32 pv;
        if (Pp < 200)      pv = ldc_u(p.ff2 + ((size_t)t*64 + b)*240 + 40 + Pp);
        else if (Pp < 400) pv = ldc_u(p.ff3 + ((size_t)t*64 + b)*240 + 40 + (Pp-200));
        else               pv = ldc_u(p.h3r + ((size_t)(t&63)*64 + b)*200 + (Pp-400));
        *(u32*)(pan + b*SWO + 2*pl) = pv;
      }
      __syncthreads();
      const _Float16* wp = wofg + ((size_t)(ph*60)*32 + cg)*16;
#pragma unroll 3
      for (int k = 0; k < 240; k += 4) {
        h4 wa = *(const h4*)(wp);
        h4 wb = *(const h4*)(wp+4);
        h4 wc = *(const h4*)(wp+8);
        h4 wd = *(const h4*)(wp+12);
        wp += 512;
#pragma unroll
        for (int r = 0; r < 8; ++r) {
          h4 a = *(const h4*)(pan + (bg*8+r)*SWO + k);
          h2 al = lo4(a), ah = hi4(a);
          acc[r][0] = dot2(al, lo4(wa), acc[r][0]); acc[r][0] = dot2(ah, hi4(wa), acc[r][0]);
          acc[r][1] = dot2(al, lo4(wb), acc[r][1]); acc[r][1] = dot2(ah, hi4(wb), acc[r][1]);
          acc[r][2] = dot2(al, lo4(wc), acc[r][2]); acc[r][2] = dot2(ah, hi4(wc), acc[r][2]);
          acc[r][3] = dot2(al, lo4(wd), acc[r][3]); acc[r][3] = dot2(ah, hi4(wd), acc[r][3]);
        }
      }
      __syncthreads();
    }
#pragma unroll
    for (int r = 0; r < 8; ++r)
#pragma unroll
      for (int j = 0; j < 4; ++j) {
        int c = c0 + j;
        if (c < 121)
          p.out_y[((size_t)(bg*8+r)*T_ + t)*OUT_ + c] = acc[r][j] + bo[j];
      }
    __syncthreads();
    set_flag(p.flags, 4, t, 0);
  }
}

__global__ __launch_bounds__(256) void hw_pipeline(P p) {
  __shared__ __align__(16) char smem_raw[SMEM_BYTES];
  const int bid = blockIdx.x;
  if (bid < G1) lstm1_role(p, bid, smem_raw);
  else if (bid < G1+G2) lstm_role<2>(p, bid - G1, smem_raw);
  else if (bid < G1+G2+G3) lstm_role<3>(p, bid - G1 - G2, smem_raw);
  else out_role(p, bid - G1 - G2 - G3, smem_raw);
}

extern "C" void kernel_launch(void* const* d_in, const int* in_sizes, int n_in,
                              void* d_out, int out_size, void* d_ws, size_t ws_size,
                              hipStream_t stream) {
  (void)in_sizes; (void)n_in; (void)out_size; (void)ws_size;
  P p;
  p.x = (const float*)d_in[0];
  p.text = (const int*)d_in[1];
  p.tmask = (const float*)d_in[2];
  p.h0 = (const float*)d_in[3];
  p.c0 = (const float*)d_in[4];
  p.pwv = (const float*)d_in[5];
  p.pkap = (const float*)d_in[6];
  p.wih1 = (const float*)d_in[7];  p.whh1 = (const float*)d_in[8];
  p.bih1 = (const float*)d_in[9];  p.bhh1 = (const float*)d_in[10];
  p.wih2 = (const float*)d_in[11]; p.whh2 = (const float*)d_in[12];
  p.bih2 = (const float*)d_in[13]; p.bhh2 = (const float*)d_in[14];
  p.wih3 = (const float*)d_in[15]; p.whh3 = (const float*)d_in[16];
  p.bih3 = (const float*)d_in[17]; p.bhh3 = (const float*)d_in[18];
  p.wwin = (const float*)d_in[19]; p.bwin = (const float*)d_in[20];
  p.wout = (const float*)d_in[21]; p.bout = (const float*)d_in[22];
  float* out = (float*)d_out;
  p.out_y  = out;
  p.out_wv = out + (size_t)B_*T_*OUT_;
  p.out_kap = p.out_wv + (size_t)B_*T_*V_;
  char* ws = (char*)d_ws;
  p.flags = (u32*)(ws + FLAGS_B);
  p.hs1 = (u32*)(ws + HS1P_B);
  p.hs2 = (u32*)(ws + HS2P_B);
  p.hs3 = (u32*)(ws + HS3P_B);
  p.w1f = (_Float16*)(ws + W1F_B);
  p.w2f = (_Float16*)(ws + W2F_B);
  p.w3f = (_Float16*)(ws + W3F_B);
  p.wof = (_Float16*)(ws + WOF_B);
  p.wwf = (u32*)(ws + WWF_B);
  p.ff2 = (u32*)(ws + FF2_B);
  p.ff3 = (u32*)(ws + FF3_B);
  p.h3r = (u32*)(ws + H3R_B);
  (void)hipMemsetAsync(ws + FLAGS_B, 0, FLAGS_SZ, stream);
  hipLaunchKernelGGL(hw_pipeline, dim3(NBLK), dim3(256), 0, stream, p);
}

// Round 9
// 23000.243 us; speedup vs baseline: 3.2650x; 3.2650x over previous
//
#include <hip/hip_runtime.h>
#include <hip/hip_bf16.h>
#include <cstdint>
#include <cstddef>
#include <cstring>

using u32 = unsigned int;
using u64 = unsigned long long;
typedef _Float16 h2 __attribute__((ext_vector_type(2)));
typedef _Float16 h4 __attribute__((ext_vector_type(4)));

constexpr int B_=64, T_=600, U_=50, V_=77, H_=400, OUT_=121;
constexpr int G1=50, GPA=8, G2=50, G3=50, GOUT=8;
constexpr int NBLK = G1+GPA+G2+G3+GOUT; // 166
constexpr int TF0=50, TF1=8, TF2=50, TF3=50;

// ---- ws byte offsets ----
constexpr size_t FLAGS_B = 0;                        // [stage4][t600][prod64] 16B slots
constexpr size_t FLAGS_SZ = 4ull*600*64*16;          // 2,457,600
constexpr size_t W1F_B  = FLAGS_SZ;                  // interleaved f16 [kk][cu8][g4][h4]
constexpr size_t W1WG   = 120ull*128;
constexpr size_t W2F_B  = W1F_B + 50ull*W1WG*2;
constexpr size_t W2WG   = 220ull*128;
constexpr size_t W3F_B  = W2F_B + 50ull*W2WG*2;
constexpr size_t WOF_B  = W3F_B + 50ull*W2WG*2;      // 8 * [kk300][cg32][c4][h4]
constexpr size_t WOWG   = 300ull*32*16;
constexpr size_t WWF_B  = WOF_B + 8ull*WOWG*2;       // 8 * u32 [kk200][m32]
constexpr size_t WWFWG  = 200ull*32;
// write-once, t-indexed inter-stage buffers (consumers: plain CACHED loads)
constexpr size_t FWV_B  = WWF_B + 8ull*WWFWG*4;      // u32 [600][64][40]  (wv+x, PA)
constexpr size_t FH1_B  = FWV_B + 600ull*64*40*4;    // u32 [600][64][200] (h1, L1)
constexpr size_t FH2_B  = FH1_B + 600ull*64*200*4;   // (h2, L2)
constexpr size_t FH3_B  = FH2_B + 600ull*64*200*4;   // (h3, L3)
// total ~110.6 MB

// LDS strides (f16 units)
constexpr int SW1 = 180;   // L1 panels (160 dims)
constexpr int SW2 = 228;   // L2/L3 panels (220 dims)
constexpr int SWO = 244;   // OUT (240 dims)
constexpr int SMEM_BYTES = 58368;

struct P {
  const float *x, *tmask, *h0, *c0, *pwv, *pkap;
  const int *text;
  const float *wih1,*whh1,*bih1,*bhh1;
  const float *wih2,*whh2,*bih2,*bhh2;
  const float *wih3,*whh3,*bih3,*bhh3;
  const float *wwin,*bwin,*wout,*bout;
  float *out_y,*out_wv,*out_kap;
  _Float16 *w1f,*w2f,*w3f,*wof;
  u32 *wwf;
  u32 *fwv,*fh1,*fh2,*fh3;
  u32 *flags;
};

__device__ __forceinline__ u32 ldc_u(const u32* p) {
  return __hip_atomic_load((u32*)p, __ATOMIC_RELAXED, __HIP_MEMORY_SCOPE_AGENT);
}
__device__ __forceinline__ void stc_u(u32* p, u32 v) {
  __hip_atomic_store(p, v, __ATOMIC_RELAXED, __HIP_MEMORY_SCOPE_AGENT);
}
__device__ __forceinline__ float sigm(float x) { return 1.f/(1.f+__expf(-x)); }
__device__ __forceinline__ h2 pk16(float a, float b) {
  auto t = __builtin_amdgcn_cvt_pkrtz(a, b);
  h2 r; memcpy(&r, &t, 4); return r;
}
__device__ __forceinline__ u32 h2u(h2 v) { u32 r; memcpy(&r, &v, 4); return r; }
__device__ __forceinline__ h2 u2h(u32 v) { h2 r; memcpy(&r, &v, 4); return r; }
__device__ __forceinline__ u32 pkf(float a, float b) { return h2u(pk16(a, b)); }
__device__ __forceinline__ float dot2(h2 a, h2 b, float c) { return __builtin_amdgcn_fdot2(a, b, c, false); }
__device__ __forceinline__ h2 lo4(h4 v) { return __builtin_shufflevector(v, v, 0, 1); }
__device__ __forceinline__ h2 hi4(h4 v) { return __builtin_shufflevector(v, v, 2, 3); }

__device__ __forceinline__ void poll_all(u32* flags, int stage, int t, int n) {
  const size_t base = ((size_t)stage*600 + t) * 64;
  for (int i = threadIdx.x; i < n; i += 256) {
    const u32* s = flags + ((base + i) << 2);
    while (ldc_u(s) == 0) {}
  }
}
__device__ __forceinline__ void set_flag(u32* flags, int stage, int t, int prod) {
  if (threadIdx.x == 0)
    stc_u(flags + ((((size_t)stage*600 + t)*64 + prod) << 2), 1u);
}

template<int PH>
__device__ __forceinline__ void gemm_phase(const _Float16* pan, int SWf, const _Float16* wgW,
                                           int cu, int kbase, int b0, float acc[2][4]) {
  const _Float16* a0 = pan + b0*SWf;
  const _Float16* a1 = a0 + SWf;
  const _Float16* wp = wgW + ((size_t)(kbase >> 2) * 8 + cu) * 16;
#pragma unroll 4
  for (int k = 0; k < PH; k += 4) {
    h4 x0 = *(const h4*)(a0+k), x1 = *(const h4*)(a1+k);
    h4 wa = *(const h4*)(wp);
    h4 wb = *(const h4*)(wp+4);
    h4 wc = *(const h4*)(wp+8);
    h4 wd = *(const h4*)(wp+12);
    wp += 128;
    h2 x0l=lo4(x0), x0h=hi4(x0), x1l=lo4(x1), x1h=hi4(x1);
    acc[0][0]=dot2(x0l,lo4(wa),acc[0][0]); acc[0][0]=dot2(x0h,hi4(wa),acc[0][0]);
    acc[0][1]=dot2(x0l,lo4(wb),acc[0][1]); acc[0][1]=dot2(x0h,hi4(wb),acc[0][1]);
    acc[0][2]=dot2(x0l,lo4(wc),acc[0][2]); acc[0][2]=dot2(x0h,hi4(wc),acc[0][2]);
    acc[0][3]=dot2(x0l,lo4(wd),acc[0][3]); acc[0][3]=dot2(x0h,hi4(wd),acc[0][3]);
    acc[1][0]=dot2(x1l,lo4(wa),acc[1][0]); acc[1][0]=dot2(x1h,hi4(wa),acc[1][0]);
    acc[1][1]=dot2(x1l,lo4(wb),acc[1][1]); acc[1][1]=dot2(x1h,hi4(wb),acc[1][1]);
    acc[1][2]=dot2(x1l,lo4(wc),acc[1][2]); acc[1][2]=dot2(x1h,hi4(wc),acc[1][2]);
    acc[1][3]=dot2(x1l,lo4(wd),acc[1][3]); acc[1][3]=dot2(x1h,hi4(wd),acc[1][3]);
  }
}

// ================= L1 =================
__device__ void lstm1_role(const P& p, int wg, char* smem) {
  const int tid = threadIdx.x, cg = tid & 7, tb = tid >> 3;
  const int u = wg*8 + cg, b0 = tb*2;
  _Float16* panA = (_Float16*)smem;
  _Float16* panB = panA + 64*SW1;
  _Float16* wgW = p.w1f + (size_t)wg * W1WG;
  // K-order dims: [h1rec 0..399 | wv 400..476 | x 477..479]
  for (int e = tid; e < 32*480; e += 256) {
    int lr = e / 480, j = e - lr*480;
    int g = lr >> 3, cu = lr & 7;
    int r = g*400 + wg*8 + cu;
    float v;
    if (j < 400)      v = p.whh1[(size_t)r*400 + j];
    else if (j < 477) v = p.wih1[(size_t)r*80 + 3 + (j-400)];
    else              v = p.wih1[(size_t)r*80 + (j-477)];
    wgW[((size_t)(j>>2)*8 + cu)*16 + g*4 + (j&3)] = (_Float16)v;
  }
  float bsum[4];
#pragma unroll
  for (int g = 0; g < 4; ++g) bsum[g] = p.bih1[g*400+u] + p.bhh1[g*400+u];
  float creg[2];
  creg[0] = p.c0[(size_t)b0*H_ + u];
  creg[1] = p.c0[(size_t)(b0+1)*H_ + u];
  __syncthreads();

  for (int t = 0; t < T_; ++t) {
    float acc[2][4] = {{0,0,0,0},{0,0,0,0}};
    if (t > 0) poll_all(p.flags, 0, t-1, TF0);
    __syncthreads();
    const u32* h1p = p.fh1 + (size_t)(t-1)*64*200;   // valid t>0
    // ph0: rec pairs 0..79 -> panA (cached loads)
    {
      u32 tmp[20];
#pragma unroll
      for (int it = 0; it < 20; ++it) {
        int idx = tid + it*256; int b = idx/80, q = idx - b*80;
        if (t == 0) { float2 f = *(const float2*)(p.h0 + (size_t)b*H_ + 2*q); tmp[it] = pkf(f.x, f.y); }
        else tmp[it] = h1p[b*200 + q];
      }
#pragma unroll
      for (int it = 0; it < 20; ++it) {
        int idx = tid + it*256; int b = idx/80, q = idx - b*80;
        ((u32*)panA)[b*90 + q] = tmp[it];
      }
    }
    __syncthreads();
    // ph1: rec pairs 80..159 -> panB || gemm0
    {
      u32 tmp[20];
#pragma unroll
      for (int it = 0; it < 20; ++it) {
        int idx = tid + it*256; int b = idx/80, q = 80 + (idx - b*80);
        if (t == 0) { float2 f = *(const float2*)(p.h0 + (size_t)b*H_ + 2*q); tmp[it] = pkf(f.x, f.y); }
        else tmp[it] = h1p[b*200 + q];
      }
      gemm_phase<160>(panA, SW1, wgW, cg, 0, b0, acc);
#pragma unroll
      for (int it = 0; it < 20; ++it) {
        int idx = tid + it*256; int b = idx/80, q = idx - b*80;
        ((u32*)panB)[b*90 + q] = tmp[it];
      }
    }
    if (t > 0) poll_all(p.flags, 1, t-1, TF1);
    __syncthreads();
    // ph2: [rec 160..199 | wv(t-1)+x(t) 40] -> panA || gemm1
    {
      u32 tmpA[10], tmpB[10];
#pragma unroll
      for (int it = 0; it < 10; ++it) {
        int idx = tid + it*256; int b = idx/40, q = idx - b*40;
        if (t == 0) { float2 f = *(const float2*)(p.h0 + (size_t)b*H_ + 2*(160+q)); tmpA[it] = pkf(f.x, f.y); }
        else tmpA[it] = h1p[b*200 + 160 + q];
      }
#pragma unroll
      for (int it = 0; it < 10; ++it) {
        int idx = tid + it*256; int b = idx/40, q = idx - b*40;
        u32 v;
        if (q < 38) {
          if (t == 0) v = pkf(p.pwv[(size_t)b*V_ + 2*q], p.pwv[(size_t)b*V_ + 2*q + 1]);
          else v = p.fwv[((size_t)(t-1)*64 + b)*40 + q];
        } else if (q == 38) {
          float wv76 = (t == 0) ? p.pwv[(size_t)b*V_ + 76]
                                : (float)u2h(p.fwv[((size_t)(t-1)*64 + b)*40 + 38]).x;
          v = pkf(wv76, p.x[((size_t)b*T_ + t)*3 + 0]);
        } else {
          v = pkf(p.x[((size_t)b*T_ + t)*3 + 1], p.x[((size_t)b*T_ + t)*3 + 2]);
        }
        tmpB[it] = v;
      }
      gemm_phase<160>(panB, SW1, wgW, cg, 160, b0, acc);
#pragma unroll
      for (int it = 0; it < 10; ++it) {
        int idx = tid + it*256; int b = idx/40, q = idx - b*40;
        ((u32*)panA)[b*90 + q] = tmpA[it];
        ((u32*)panA)[b*90 + 40 + q] = tmpB[it];
      }
    }
    __syncthreads();
    gemm_phase<160>(panA, SW1, wgW, cg, 320, b0, acc);

    float hn[2];
#pragma unroll
    for (int r = 0; r < 2; ++r) {
      float gi = acc[r][0]+bsum[0], gf = acc[r][1]+bsum[1];
      float gg = acc[r][2]+bsum[2], go = acc[r][3]+bsum[3];
      float cn = sigm(gf)*creg[r] + sigm(gi)*tanhf(gg);
      creg[r] = cn;
      hn[r] = sigm(go)*tanhf(cn);
    }
    {
      float h0p = __shfl_xor(hn[0], 1, 64);
      float h1x = __shfl_xor(hn[1], 1, 64);
      if ((cg & 1) == 0) {
        const int pi = wg*4 + (cg >> 1);
        stc_u(p.fh1 + ((size_t)t*64 + b0)*200 + pi, pkf(hn[0], h0p));
        stc_u(p.fh1 + ((size_t)t*64 + b0+1)*200 + pi, pkf(hn[1], h1x));
      }
    }
    __syncthreads();
    set_flag(p.flags, 0, t, wg);
  }
}

// ================= PA (attention) =================
__device__ void pa_role(const P& p, int pa, char* smem) {
  const int tid = threadIdx.x;
  const int b0p = pa*8;
  u32* hsm   = (u32*)smem;                 // [8][200]
  float* mixL = (float*)(smem + 6400);     // 240
  float* kapL = (float*)(smem + 7360);     // 80
  float* phiL = (float*)(smem + 7680);     // 400
  float* wvs  = (float*)(smem + 9280);     // 616
  u32* wwf = p.wwf + (size_t)pa * WWFWG;
  for (int e = tid; e < 200*30; e += 256) {
    int kk = e / 30, m = e - (e/30)*30;
    wwf[(size_t)kk*32 + m] = pkf(p.wwin[(size_t)m*400 + 2*kk], p.wwin[(size_t)m*400 + 2*kk + 1]);
  }
  float kap_reg = 0.f;
  if (tid < 80) kap_reg = p.pkap[(size_t)(b0p + tid/10)*10 + (tid % 10)];
  __syncthreads();

  for (int t = 0; t < T_; ++t) {
    poll_all(p.flags, 0, t, TF0);
    __syncthreads();
    for (int e = tid; e < 1600; e += 256) {
      int bl = e / 200, q = e - bl*200;
      hsm[bl*200 + q] = p.fh1[((size_t)t*64 + b0p + bl)*200 + q];   // cached
    }
    __syncthreads();
    if (tid < 240) {
      int bl = tid / 30, m = tid - (tid/30)*30;
      const u32* hp = hsm + bl*200;
      float d0=0.f, d1=0.f, d2=0.f, d3=0.f;
#pragma unroll 4
      for (int kk = 0; kk < 200; kk += 4) {
        d0 = dot2(u2h(hp[kk]),   u2h(wwf[(size_t)(kk)*32 + m]),   d0);
        d1 = dot2(u2h(hp[kk+1]), u2h(wwf[(size_t)(kk+1)*32 + m]), d1);
        d2 = dot2(u2h(hp[kk+2]), u2h(wwf[(size_t)(kk+2)*32 + m]), d2);
        d3 = dot2(u2h(hp[kk+3]), u2h(wwf[(size_t)(kk+3)*32 + m]), d3);
      }
      mixL[tid] = __expf((d0+d1)+(d2+d3) + p.bwin[m]);
    }
    __syncthreads();
    if (tid < 80) {
      int bl = tid/10, k = tid - (tid/10)*10;
      kap_reg += mixL[bl*30 + 20 + k];
      kapL[bl*10 + k] = kap_reg;
      if (t == T_-1) p.out_kap[(size_t)(b0p+bl)*10 + k] = kap_reg;
    }
    __syncthreads();
    for (int i = tid; i < 400; i += 256) {
      int bl = i / 50, uu = i - (i/50)*50;
      float s = 0.f; const float fu = (float)uu;
#pragma unroll
      for (int k = 0; k < 10; ++k) {
        float df = kapL[bl*10+k] - fu;
        s += mixL[bl*30+k] * __expf(-mixL[bl*30+10+k]*df*df);
      }
      phiL[i] = s * p.tmask[(size_t)(b0p+bl)*U_ + uu];
    }
    for (int i = tid; i < 616; i += 256) wvs[i] = 0.f;
    __syncthreads();
    if (tid < 8) {
      int b = b0p + tid;
      for (int uu = 0; uu < U_; ++uu)
        wvs[tid*77 + p.text[(size_t)b*U_ + uu]] += phiL[tid*50 + uu];
    }
    __syncthreads();
    for (int i = tid; i < 616; i += 256) {
      int bl = i / 77, v = i - (i/77)*77;
      p.out_wv[((size_t)(b0p+bl)*T_ + t)*V_ + v] = wvs[i];   // output, plain
    }
    for (int i = tid; i < 320; i += 256) {
      int bl = i / 40, pr = i - (i/40)*40;
      int b = b0p + bl;
      float f0, f1;
      if (pr < 38)       { f0 = wvs[bl*77 + 2*pr]; f1 = wvs[bl*77 + 2*pr + 1]; }
      else if (pr == 38) { f0 = wvs[bl*77 + 76];   f1 = p.x[((size_t)b*T_ + t)*3 + 0]; }
      else               { f0 = p.x[((size_t)b*T_ + t)*3 + 1]; f1 = p.x[((size_t)b*T_ + t)*3 + 2]; }
      stc_u(p.fwv + ((size_t)t*64 + b)*40 + pr, pkf(f0, f1));
    }
    __syncthreads();
    set_flag(p.flags, 1, t, pa);
  }
}

// ================= L2/L3 =================
template <int L>
__device__ void lstm_role(const P& p, int wg, char* smem) {
  const int tid = threadIdx.x, cg = tid & 7, tb = tid >> 3;
  const int u = wg*8 + cg, b0 = tb*2;
  constexpr int STG = (L==2) ? 2 : 3;
  _Float16* wgW = ((L==2) ? p.w2f : p.w3f) + (size_t)wg * W2WG;
  const float* wih = (L==2) ? p.wih2 : p.wih3;
  const float* whh = (L==2) ? p.whh2 : p.whh3;
  const float* bih = (L==2) ? p.bih2 : p.bih3;
  const float* bhh = (L==2) ? p.bhh2 : p.bhh3;
  const u32* hin = (L==2) ? p.fh1 : p.fh2;
  u32* rec = (L==2) ? p.fh2 : p.fh3;     // own-layer array (write + recurrent read)
  _Float16* panA = (_Float16*)smem;
  _Float16* panB = panA + 64*SW2;

  // K-order dims: [wv 0..76 | x 77..79 | hin 80..479 | hrec 480..879]
  for (int e = tid; e < 32*880; e += 256) {
    int lr = e / 880, j = e - lr*880;
    int g = lr >> 3, cu = lr & 7;
    int r = g*400 + wg*8 + cu;
    float v;
    if (j < 77)       v = wih[(size_t)r*480 + 403 + j];
    else if (j < 80)  v = wih[(size_t)r*480 + (j-77)];
    else if (j < 480) v = wih[(size_t)r*480 + 3 + (j-80)];
    else              v = whh[(size_t)r*400 + (j-480)];
    wgW[((size_t)(j>>2)*8 + cu)*16 + g*4 + (j&3)] = (_Float16)v;
  }
  float bsum[4];
#pragma unroll
  for (int g = 0; g < 4; ++g) bsum[g] = bih[g*400+u] + bhh[g*400+u];
  float creg[2];
  creg[0] = p.c0[(size_t)(L-1)*B_*H_ + (size_t)b0*H_ + u];
  creg[1] = p.c0[(size_t)(L-1)*B_*H_ + (size_t)(b0+1)*H_ + u];
  __syncthreads();

  for (int t = 0; t < T_; ++t) {
    float acc[2][4] = {{0,0,0,0},{0,0,0,0}};
    if (L == 2) poll_all(p.flags, 1, t, TF1);      // implies stage0(t)
    else        poll_all(p.flags, 2, t, TF2);
    __syncthreads();
    const u32* fwvt = p.fwv + (size_t)t*64*40;
    const u32* hint = hin + (size_t)t*64*200;
    const u32* rect = rec + (size_t)(t-1)*64*200;  // valid t>0
    const float* h0f = p.h0 + (size_t)(L-1)*B_*H_;
    // ph0: pairs 0..109 = [wv+x 40 | hin 0..69]
    {
      u32 tmp[28];
#pragma unroll
      for (int it = 0; it < 28; ++it) {
        int idx = tid + it*256; if (idx >= 7040) break;
        int b = idx/110, pl = idx - b*110;
        tmp[it] = (pl < 40) ? fwvt[b*40 + pl] : hint[b*200 + (pl-40)];
      }
#pragma unroll
      for (int it = 0; it < 28; ++it) {
        int idx = tid + it*256; if (idx >= 7040) break;
        int b = idx/110, pl = idx - b*110;
        ((u32*)panA)[b*114 + pl] = tmp[it];
      }
    }
    __syncthreads();
    // ph1: pairs 110..219 = hin 70..179 || gemm0
    {
      u32 tmp[28];
#pragma unroll
      for (int it = 0; it < 28; ++it) {
        int idx = tid + it*256; if (idx >= 7040) break;
        int b = idx/110, pl = idx - b*110;
        tmp[it] = hint[b*200 + 70 + pl];
      }
      gemm_phase<220>(panA, SW2, wgW, cg, 0, b0, acc);
#pragma unroll
      for (int it = 0; it < 28; ++it) {
        int idx = tid + it*256; if (idx >= 7040) break;
        int b = idx/110, pl = idx - b*110;
        ((u32*)panB)[b*114 + pl] = tmp[it];
      }
    }
    if (t > 0) poll_all(p.flags, STG, t-1, 50);
    __syncthreads();
    // ph2: pairs 220..329 = [hin 180..199 | rec 0..89] || gemm1
    {
      u32 tmp[28];
#pragma unroll
      for (int it = 0; it < 28; ++it) {
        int idx = tid + it*256; if (idx >= 7040) break;
        int b = idx/110, pl = idx - b*110;
        u32 v;
        if (pl < 20) v = hint[b*200 + 180 + pl];
        else if (t == 0) { float2 f = *(const float2*)(h0f + (size_t)b*H_ + 2*(pl-20)); v = pkf(f.x, f.y); }
        else v = rect[b*200 + (pl-20)];
        tmp[it] = v;
      }
      gemm_phase<220>(panB, SW2, wgW, cg, 220, b0, acc);
#pragma unroll
      for (int it = 0; it < 28; ++it) {
        int idx = tid + it*256; if (idx >= 7040) break;
        int b = idx/110, pl = idx - b*110;
        ((u32*)panA)[b*114 + pl] = tmp[it];
      }
    }
    __syncthreads();
    // ph3: pairs 330..439 = rec 90..199 || gemm2
    {
      u32 tmp[28];
#pragma unroll
      for (int it = 0; it < 28; ++it) {
        int idx = tid + it*256; if (idx >= 7040) break;
        int b = idx/110, pl = idx - b*110;
        u32 v;
        if (t == 0) { float2 f = *(const float2*)(h0f + (size_t)b*H_ + 2*(90+pl)); v = pkf(f.x, f.y); }
        else v = rect[b*200 + 90 + pl];
        tmp[it] = v;
      }
      gemm_phase<220>(panA, SW2, wgW, cg, 440, b0, acc);
#pragma unroll
      for (int it = 0; it < 28; ++it) {
        int idx = tid + it*256; if (idx >= 7040) break;
        int b = idx/110, pl = idx - b*110;
        ((u32*)panB)[b*114 + pl] = tmp[it];
      }
    }
    __syncthreads();
    gemm_phase<220>(panB, SW2, wgW, cg, 660, b0, acc);

    float hn[2];
#pragma unroll
    for (int r = 0; r < 2; ++r) {
      float gi = acc[r][0]+bsum[0], gf = acc[r][1]+bsum[1];
      float gg = acc[r][2]+bsum[2], go = acc[r][3]+bsum[3];
      float cn = sigm(gf)*creg[r] + sigm(gi)*tanhf(gg);
      creg[r] = cn;
      hn[r] = sigm(go)*tanhf(cn);
    }
    {
      float h0p = __shfl_xor(hn[0], 1, 64);
      float h1x = __shfl_xor(hn[1], 1, 64);
      if ((cg & 1) == 0) {
        const int pi = wg*4 + (cg >> 1);
        stc_u(rec + ((size_t)t*64 + b0)*200 + pi, pkf(hn[0], h0p));
        stc_u(rec + ((size_t)t*64 + b0+1)*200 + pi, pkf(hn[1], h1x));
      }
    }
    __syncthreads();
    set_flag(p.flags, STG, t, wg);
  }
}

// ================= OUT =================
__device__ void out_role(const P& p, int g, char* smem) {
  const int tid = threadIdx.x;
  const int cg = tid & 31, bg = tid >> 5;
  const int c0 = cg*4;
  _Float16* pan = (_Float16*)smem;
  _Float16* wofg = p.wof + (size_t)g*WOWG;
  for (int e = tid; e < 300*32*16; e += 256) {
    int kk = e >> 9, rem = e & 511;
    int cgi = rem >> 4, j4 = rem & 15;
    int j = j4 >> 2, kc = j4 & 3;
    int c = cgi*4 + j; if (c > 120) c = 120;
    wofg[e] = (_Float16)p.wout[(size_t)c*1200 + kk*4 + kc];
  }
  float bo[4];
#pragma unroll
  for (int j = 0; j < 4; ++j) {
    int c = c0 + j; if (c > 120) c = 120;
    bo[j] = p.bout[c];
  }
  __syncthreads();

  for (int t = g; t < T_; t += GOUT) {
    poll_all(p.flags, 3, t, TF3);   // implies stages 0..2 transitively
    __syncthreads();
    float acc[8][4];
#pragma unroll
    for (int r = 0; r < 8; ++r)
#pragma unroll
      for (int j = 0; j < 4; ++j) acc[r][j] = 0.f;

    for (int ph = 0; ph < 5; ++ph) {
      for (int idx = tid; idx < 7680; idx += 256) {
        int b = idx / 120, pl = idx - b*120;
        int Pp = ph*120 + pl;
        u32 pv;
        if (Pp < 200)      pv = p.fh1[((size_t)t*64 + b)*200 + Pp];
        else if (Pp < 400) pv = p.fh2[((size_t)t*64 + b)*200 + (Pp-200)];
        else               pv = p.fh3[((size_t)t*64 + b)*200 + (Pp-400)];
        ((u32*)pan)[b*122 + pl] = pv;
      }
      __syncthreads();
      const _Float16* wp = wofg + ((size_t)(ph*60)*32 + cg)*16;
#pragma unroll 3
      for (int k = 0; k < 240; k += 4) {
        h4 wa = *(const h4*)(wp);
        h4 wb = *(const h4*)(wp+4);
        h4 wc = *(const h4*)(wp+8);
        h4 wd = *(const h4*)(wp+12);
        wp += 512;
#pragma unroll
        for (int r = 0; r < 8; ++r) {
          h4 a = *(const h4*)(pan + (bg*8+r)*SWO + k);
          h2 al = lo4(a), ah = hi4(a);
          acc[r][0] = dot2(al, lo4(wa), acc[r][0]); acc[r][0] = dot2(ah, hi4(wa), acc[r][0]);
          acc[r][1] = dot2(al, lo4(wb), acc[r][1]); acc[r][1] = dot2(ah, hi4(wb), acc[r][1]);
          acc[r][2] = dot2(al, lo4(wc), acc[r][2]); acc[r][2] = dot2(ah, hi4(wc), acc[r][2]);
          acc[r][3] = dot2(al, lo4(wd), acc[r][3]); acc[r][3] = dot2(ah, hi4(wd), acc[r][3]);
        }
      }
      __syncthreads();
    }
#pragma unroll
    for (int r = 0; r < 8; ++r)
#pragma unroll
      for (int j = 0; j < 4; ++j) {
        int c = c0 + j;
        if (c < 121)
          p.out_y[((size_t)(bg*8+r)*T_ + t)*OUT_ + c] = acc[r][j] + bo[j];
      }
    __syncthreads();
  }
}

__global__ __launch_bounds__(256) void hw_pipeline(P p) {
  __shared__ __align__(16) char smem_raw[SMEM_BYTES];
  const int bid = blockIdx.x;
  if (bid < G1) lstm1_role(p, bid, smem_raw);
  else if (bid < G1+GPA) pa_role(p, bid - G1, smem_raw);
  else if (bid < G1+GPA+G2) lstm_role<2>(p, bid - G1 - GPA, smem_raw);
  else if (bid < G1+GPA+G2+G3) lstm_role<3>(p, bid - G1 - GPA - G2, smem_raw);
  else out_role(p, bid - G1 - GPA - G2 - G3, smem_raw);
}

extern "C" void kernel_launch(void* const* d_in, const int* in_sizes, int n_in,
                              void* d_out, int out_size, void* d_ws, size_t ws_size,
                              hipStream_t stream) {
  (void)in_sizes; (void)n_in; (void)out_size; (void)ws_size;
  P p;
  p.x = (const float*)d_in[0];
  p.text = (const int*)d_in[1];
  p.tmask = (const float*)d_in[2];
  p.h0 = (const float*)d_in[3];
  p.c0 = (const float*)d_in[4];
  p.pwv = (const float*)d_in[5];
  p.pkap = (const float*)d_in[6];
  p.wih1 = (const float*)d_in[7];  p.whh1 = (const float*)d_in[8];
  p.bih1 = (const float*)d_in[9];  p.bhh1 = (const float*)d_in[10];
  p.wih2 = (const float*)d_in[11]; p.whh2 = (const float*)d_in[12];
  p.bih2 = (const float*)d_in[13]; p.bhh2 = (const float*)d_in[14];
  p.wih3 = (const float*)d_in[15]; p.whh3 = (const float*)d_in[16];
  p.bih3 = (const float*)d_in[17]; p.bhh3 = (const float*)d_in[18];
  p.wwin = (const float*)d_in[19]; p.bwin = (const float*)d_in[20];
  p.wout = (const float*)d_in[21]; p.bout = (const float*)d_in[22];
  float* out = (float*)d_out;
  p.out_y  = out;
  p.out_wv = out + (size_t)B_*T_*OUT_;
  p.out_kap = p.out_wv + (size_t)B_*T_*V_;
  char* ws = (char*)d_ws;
  p.flags = (u32*)(ws + FLAGS_B);
  p.w1f = (_Float16*)(ws + W1F_B);
  p.w2f = (_Float16*)(ws + W2F_B);
  p.w3f = (_Float16*)(ws + W3F_B);
  p.wof = (_Float16*)(ws + WOF_B);
  p.wwf = (u32*)(ws + WWF_B);
  p.fwv = (u32*)(ws + FWV_B);
  p.fh1 = (u32*)(ws + FH1_B);
  p.fh2 = (u32*)(ws + FH2_B);
  p.fh3 = (u32*)(ws + FH3_B);
  (void)hipMemsetAsync(ws + FLAGS_B, 0, FLAGS_SZ, stream);
  hipLaunchKernelGGL(hw_pipeline, dim3(NBLK), dim3(256), 0, stream, p);
}